// Round 9
// baseline (31.591 us; speedup 1.0000x reference)
//
#include <hip/hip_runtime.h>

// a,p,n: [16,3,512,512] f32. 8x8 grid of 64x64 base blocks per (b,c) image.
#define WW 512
#define IMG_F 262144            // 512*512 floats per (b,c)
#define NWG 3072                // 48 images * 64 stripes (8 rows each)
#define TOTAL_PIX 12582912.0f   // 16*3*512*512

// Kernel 1: contiguous-stripe streaming. WG g owns image bc=g/64, stripe
// s=g%64 -> rows [8s, 8s+8) x all 512 cols = 16 KB *sequential* per array.
// Each thread's 4 loads (stride 256 float4) all land in ONE column-block
// cb=(tid&127)>>4, so a 16-lane-group reduce + LDS combine yields the 8
// per-(stripe, col-block) partial pairs.
__global__ __launch_bounds__(256) void hd_stripe_sums(
    const float* __restrict__ a, const float* __restrict__ p,
    const float* __restrict__ n, float2* __restrict__ part)
{
    const int g   = blockIdx.x;        // 0..3071
    const int bc  = g >> 6;            // image
    const int s   = g & 63;            // stripe
    const int rb  = s >> 3, sub = s & 7;
    const int tid = threadIdx.x;

    const size_t base4 = ((size_t)bc * IMG_F + (size_t)s * 4096) >> 2; // float4 units
    const float4* pa = (const float4*)a + base4 + tid;
    const float4* pp = (const float4*)p + base4 + tid;
    const float4* pn = (const float4*)n + base4 + tid;

    float4 va0 = pa[0], va1 = pa[256], va2 = pa[512], va3 = pa[768];
    float4 vn0 = pn[0], vn1 = pn[256], vn2 = pn[512], vn3 = pn[768];
    float4 vp0 = pp[0], vp1 = pp[256], vp2 = pp[512], vp3 = pp[768];

    float s1, s2;
    s1  = fabsf(vn0.x - va0.x) + fabsf(vn0.y - va0.y) + fabsf(vn0.z - va0.z) + fabsf(vn0.w - va0.w);
    s1 += fabsf(vn1.x - va1.x) + fabsf(vn1.y - va1.y) + fabsf(vn1.z - va1.z) + fabsf(vn1.w - va1.w);
    s1 += fabsf(vn2.x - va2.x) + fabsf(vn2.y - va2.y) + fabsf(vn2.z - va2.z) + fabsf(vn2.w - va2.w);
    s1 += fabsf(vn3.x - va3.x) + fabsf(vn3.y - va3.y) + fabsf(vn3.z - va3.z) + fabsf(vn3.w - va3.w);
    s2  = fabsf(va0.x - vp0.x) + fabsf(va0.y - vp0.y) + fabsf(va0.z - vp0.z) + fabsf(va0.w - vp0.w);
    s2 += fabsf(va1.x - vp1.x) + fabsf(va1.y - vp1.y) + fabsf(va1.z - vp1.z) + fabsf(va1.w - vp1.w);
    s2 += fabsf(va2.x - vp2.x) + fabsf(va2.y - vp2.y) + fabsf(va2.z - vp2.z) + fabsf(va2.w - vp2.w);
    s2 += fabsf(va3.x - vp3.x) + fabsf(va3.y - vp3.y) + fabsf(va3.z - vp3.z) + fabsf(va3.w - vp3.w);

    // reduce within each 16-lane group (one column-block per group)
    #pragma unroll
    for (int off = 8; off > 0; off >>= 1) {
        s1 += __shfl_xor(s1, off, 64);
        s2 += __shfl_xor(s2, off, 64);
    }
    // red[wave][group]; cb = (wave&1)*4 + group, waves w and w+2 share a cb
    __shared__ float2 red[16];
    const int wave = tid >> 6, lane = tid & 63;
    if ((lane & 15) == 0) red[wave * 4 + (lane >> 4)] = make_float2(s1, s2);
    __syncthreads();
    if (tid < 8) {
        const int cb = tid, w0 = cb >> 2, gr = cb & 3;
        float2 x = red[w0 * 4 + gr];
        float2 y = red[(w0 + 2) * 4 + gr];
        // layout: [bc][rb][cb][sub] -> finalize reads 8 consecutive float2/lane
        part[(((bc * 8 + rb) * 8 + cb) << 3) + sub] =
            make_float2(x.x + y.x, x.y + y.y);
    }
}

// Kernel 2: finalize. One wave per (b,c); lane = (i,j) on the 8x8 block grid.
// Each lane: 4 float4 loads = its block's 8 (s1,s2) sub-stripe pairs.
__global__ __launch_bounds__(1024) void hd_finalize(
    const float2* __restrict__ part, float* __restrict__ out)
{
    const int tid  = threadIdx.x;
    const int w    = tid >> 6;        // wave 0..15
    const int lane = tid & 63;
    const int i = lane >> 3, j = lane & 7;
    __shared__ float partial[16];

    float acc = 0.f;
    #pragma unroll
    for (int it = 0; it < 3; ++it) {
        const int bc = w + it * 16;
        const float4* q = (const float4*)part + ((size_t)(bc * 64 + lane) << 2);
        float4 u0 = q[0], u1 = q[1], u2 = q[2], u3 = q[3];
        // float4 packs two float2 pairs: (s1,s2,s1,s2)
        float b  = ((u0.x + u0.z) + (u1.x + u1.z)) + ((u2.x + u2.z) + (u3.x + u3.z));
        float bp = ((u0.y + u0.w) + (u1.y + u1.w)) + ((u2.y + u2.w) + (u3.y + u3.w));
        // diff = sum over 8x8 grid
        float d = b;
        #pragma unroll
        for (int off = 32; off > 0; off >>= 1) d += __shfl_xor(d, off, 64);
        // window value wv[i][j], defined for i,j<7 (else 0)
        float b_r  = __shfl(b, lane + 8, 64);
        float b_c  = __shfl(b, lane + 1, 64);
        float b_rc = __shfl(b, lane + 9, 64);
        float wv = (i < 7 && j < 7) ? (b + b_r + b_c + b_rc) / d : 0.f;
        // overlap-add + coverage
        float wv_u  = __shfl(wv, lane - 8, 64);
        float wv_l  = __shfl(wv, lane - 1, 64);
        float wv_ul = __shfl(wv, lane - 9, 64);
        float mb = wv;
        if (i > 0)          mb += wv_u;
        if (j > 0)          mb += wv_l;
        if (i > 0 && j > 0) mb += wv_ul;
        const int ci = (i == 0 || i == 7) ? 1 : 2;
        const int cj = (j == 0 || j == 7) ? 1 : 2;
        acc += (mb / (float)(ci * cj)) * bp;
    }

    #pragma unroll
    for (int off = 32; off > 0; off >>= 1) acc += __shfl_xor(acc, off, 64);
    if (lane == 0) partial[w] = acc;
    __syncthreads();
    if (tid == 0) {
        float ssum = 0.f;
        #pragma unroll
        for (int k = 0; k < 16; ++k) ssum += partial[k];
        out[0] = ssum / TOTAL_PIX;
    }
}

extern "C" void kernel_launch(void* const* d_in, const int* in_sizes, int n_in,
                              void* d_out, int out_size, void* d_ws, size_t ws_size,
                              hipStream_t stream) {
    const float* a = (const float*)d_in[0];
    const float* p = (const float*)d_in[1];
    const float* n = (const float*)d_in[2];
    float2* part = (float2*)d_ws;                 // 48*8*8*8 = 24576 float2 (192 KB)

    hd_stripe_sums<<<NWG, 256, 0, stream>>>(a, p, n, part);
    hd_finalize<<<1, 1024, 0, stream>>>(part, (float*)d_out);
}